// Round 1
// baseline (920.234 us; speedup 1.0000x reference)
//
#include <hip/hip_runtime.h>
#include <hip/hip_bf16.h>

#define BB 16384
#define KK 3
#define DD 1024
#define HH 16

typedef __attribute__((ext_vector_type(8))) short bf16x8;
typedef __attribute__((ext_vector_type(4))) float f32x4;
typedef unsigned int u32;

__device__ __forceinline__ void load_lds16(const void* g, void* l) {
  __builtin_amdgcn_global_load_lds(
      (const __attribute__((address_space(1))) u32*)g,
      (__attribute__((address_space(3))) u32*)l,
      16, 0, 0);
}

__device__ __forceinline__ unsigned short f2bf(float f) {
  __hip_bfloat16 h = __float2bfloat16(f);
  unsigned short u;
  __builtin_memcpy(&u, &h, 2);
  return u;
}

__device__ __forceinline__ float bf2f(unsigned short u) {
  union { float f; u32 i; } cv;
  cv.i = ((u32)u) << 16;
  return cv.f;
}

// ---------------------------------------------------------------- cast fp32 -> bf16
__global__ void cast_f32_bf16(const float* __restrict__ in,
                              unsigned short* __restrict__ out, int n4) {
  int stride = gridDim.x * blockDim.x;
  for (int i = blockIdx.x * blockDim.x + threadIdx.x; i < n4; i += stride) {
    float4 v = ((const float4*)in)[i];
    ushort4 o;
    o.x = f2bf(v.x);
    o.y = f2bf(v.y);
    o.z = f2bf(v.z);
    o.w = f2bf(v.w);
    ((ushort4*)out)[i] = o;
  }
}

// ---------------------------------------------------------------- GEMM: C = A @ Bt^T + bias
// A: M x K bf16 row-major. Bt: N x K bf16 row-major (i.e. B transposed).
// 128x128 tile, BK=32, 256 threads = 4 waves (2x2), each wave 64x64 (4x4 frags of 16x16).
// m97 structure: global_load_lds width=16 staging, linear LDS, 2 barriers/K-step.
template <bool OUT_F32>
__global__ __launch_bounds__(256)
void gemm_bt(const __hip_bfloat16* __restrict__ A,
             const __hip_bfloat16* __restrict__ Bt,
             const float* __restrict__ bias,
             void* __restrict__ Cout,
             int M, int N, int K) {
  __shared__ char sA[128 * 64];  // 128 rows x 32 bf16 = 64B/row
  __shared__ char sB[128 * 64];

  const int nTn = N >> 7;
  const int tm = blockIdx.x / nTn;
  const int tn = blockIdx.x % nTn;
  const int t = threadIdx.x;
  const int l = t & 63;
  const int w = t >> 6;
  const int wr = w >> 1;
  const int wc = w & 1;

  f32x4 acc[4][4] = {};

  const char* Ab = (const char*)(A + (size_t)tm * 128 * K);
  const char* Bb = (const char*)(Bt + (size_t)tn * 128 * K);
  const int lrow = t >> 2;          // staging row for chunk 0 (0..63)
  const int lcol = (t & 3) << 4;    // byte col within 64B row
  const int l15 = l & 15;
  const int kgrp = (l >> 4) << 4;   // byte offset of lane's 8-elem k-slice
  const size_t rowstride = (size_t)K * 2;

  for (int k0 = 0; k0 < K; k0 += 32) {
    const size_t gcol = (size_t)k0 * 2 + lcol;
#pragma unroll
    for (int i = 0; i < 2; ++i) {
      const int row = lrow + (i << 6);
      load_lds16(Ab + (size_t)row * rowstride + gcol, sA + row * 64 + lcol);
      load_lds16(Bb + (size_t)row * rowstride + gcol, sB + row * 64 + lcol);
    }
    __syncthreads();  // compiler drains vmcnt before barrier

    bf16x8 af[4], bfr[4];
#pragma unroll
    for (int m = 0; m < 4; ++m)
      af[m] = *(const bf16x8*)(sA + (wr * 64 + m * 16 + l15) * 64 + kgrp);
#pragma unroll
    for (int n = 0; n < 4; ++n)
      bfr[n] = *(const bf16x8*)(sB + (wc * 64 + n * 16 + l15) * 64 + kgrp);

#pragma unroll
    for (int m = 0; m < 4; ++m)
#pragma unroll
      for (int n = 0; n < 4; ++n)
        acc[m][n] = __builtin_amdgcn_mfma_f32_16x16x32_bf16(af[m], bfr[n],
                                                            acc[m][n], 0, 0, 0);
    __syncthreads();
  }

  // epilogue: C/D layout col = lane&15, row = (lane>>4)*4 + reg  [m89-verified]
  const int rbase = tm * 128 + wr * 64 + (l >> 4) * 4;
  const int cbase = tn * 128 + wc * 64 + l15;
#pragma unroll
  for (int m = 0; m < 4; ++m) {
#pragma unroll
    for (int j = 0; j < 4; ++j) {
      const size_t row = (size_t)(rbase + m * 16 + j);
#pragma unroll
      for (int n = 0; n < 4; ++n) {
        const int col = cbase + n * 16;
        float v = acc[m][n][j] + bias[col];
        if (OUT_F32)
          ((float*)Cout)[row * N + col] = v;
        else
          ((unsigned short*)Cout)[row * N + col] = f2bf(v);
      }
    }
  }
}

// ---------------------------------------------------------------- attention
// One wave per (b,h). lane = d (head dim 64). K=3 queries/keys.
__global__ __launch_bounds__(256)
void attn_kernel(const unsigned short* __restrict__ QKV,  // (B*3) x 3072
                 const unsigned short* __restrict__ Cp,   // B x 1024
                 unsigned short* __restrict__ Out) {      // (B*3) x 1024
  const int wid = (blockIdx.x * 256 + threadIdx.x) >> 6;
  const int l = threadIdx.x & 63;
  const int b = wid >> 4;   // H = 16
  const int h = wid & 15;

  const size_t qbase = (size_t)b * 3 * 3072 + h * 64 + l;
  const float c = bf2f(Cp[(size_t)b * 1024 + h * 64 + l]);

  float q[3], kc[3], vc[3];
#pragma unroll
  for (int i = 0; i < 3; ++i) {
    q[i]  = bf2f(QKV[qbase + (size_t)i * 3072]);
    kc[i] = bf2f(QKV[qbase + (size_t)i * 3072 + 1024]) * c;
    vc[i] = bf2f(QKV[qbase + (size_t)i * 3072 + 2048]) * c;
  }

  float s[9];
#pragma unroll
  for (int i = 0; i < 3; ++i)
#pragma unroll
    for (int j = 0; j < 3; ++j)
      s[i * 3 + j] = q[i] * kc[j];

  // butterfly reduce over 64 lanes (head dim)
#pragma unroll
  for (int off = 32; off > 0; off >>= 1)
#pragma unroll
    for (int e = 0; e < 9; ++e)
      s[e] += __shfl_xor(s[e], off, 64);

  const float scale = 0.125f;  // 1/sqrt(64)
  float o[3];
#pragma unroll
  for (int i = 0; i < 3; ++i) {
    float s0 = s[i * 3 + 0] * scale;
    float s1 = s[i * 3 + 1] * scale;
    float s2 = s[i * 3 + 2] * scale;
    float m = fmaxf(fmaxf(s0, s1), s2);
    float p0 = expf(s0 - m), p1 = expf(s1 - m), p2 = expf(s2 - m);
    float inv = 1.0f / (p0 + p1 + p2);
    o[i] = (p0 * vc[0] + p1 * vc[1] + p2 * vc[2]) * inv;
  }
#pragma unroll
  for (int i = 0; i < 3; ++i)
    Out[(size_t)(b * 3 + i) * 1024 + h * 64 + l] = f2bf(o[i]);
}

// ---------------------------------------------------------------- launch
extern "C" void kernel_launch(void* const* d_in, const int* in_sizes, int n_in,
                              void* d_out, int out_size, void* d_ws, size_t ws_size,
                              hipStream_t stream) {
  const float* tokens = (const float*)d_in[0];
  const float* ctx    = (const float*)d_in[1];
  const float* Wq     = (const float*)d_in[2];
  const float* bq     = (const float*)d_in[3];
  const float* Wk     = (const float*)d_in[4];
  const float* bk     = (const float*)d_in[5];
  const float* Wv     = (const float*)d_in[6];
  const float* bv     = (const float*)d_in[7];
  const float* Wc     = (const float*)d_in[8];
  const float* bc     = (const float*)d_in[9];
  const float* Wo     = (const float*)d_in[10];
  const float* bo     = (const float*)d_in[11];

  const int M  = BB * KK;   // 49152 token rows
  const int Mc = BB;        // 16384 ctx rows
  const int D  = DD;        // 1024

  char* p = (char*)d_ws;
  auto carve = [&](size_t bytes) {
    char* r = p;
    p += (bytes + 255) & ~(size_t)255;
    return r;
  };
  unsigned short* Xb   = (unsigned short*)carve((size_t)M * D * 2);      // tokens bf16; later reused as attn out
  unsigned short* Cin  = (unsigned short*)carve((size_t)Mc * D * 2);
  unsigned short* Wqkv = (unsigned short*)carve((size_t)3 * D * D * 2);
  unsigned short* Wcb  = (unsigned short*)carve((size_t)D * D * 2);
  unsigned short* Wob  = (unsigned short*)carve((size_t)D * D * 2);
  float*          bqkv = (float*)carve((size_t)3 * D * 4);
  unsigned short* QKV  = (unsigned short*)carve((size_t)M * 3 * D * 2);
  unsigned short* Cpr  = (unsigned short*)carve((size_t)Mc * D * 2);

  // casts (fp32 -> bf16); Wq/Wk/Wv concatenated -> N=3072 B^T matrix
  hipLaunchKernelGGL(cast_f32_bf16, dim3(4096), dim3(256), 0, stream, tokens, Xb, M * D / 4);
  hipLaunchKernelGGL(cast_f32_bf16, dim3(2048), dim3(256), 0, stream, ctx, Cin, Mc * D / 4);
  hipLaunchKernelGGL(cast_f32_bf16, dim3(512), dim3(256), 0, stream, Wq, Wqkv, D * D / 4);
  hipLaunchKernelGGL(cast_f32_bf16, dim3(512), dim3(256), 0, stream, Wk, Wqkv + D * D, D * D / 4);
  hipLaunchKernelGGL(cast_f32_bf16, dim3(512), dim3(256), 0, stream, Wv, Wqkv + 2 * D * D, D * D / 4);
  hipLaunchKernelGGL(cast_f32_bf16, dim3(512), dim3(256), 0, stream, Wc, Wcb, D * D / 4);
  hipLaunchKernelGGL(cast_f32_bf16, dim3(512), dim3(256), 0, stream, Wo, Wob, D * D / 4);
  hipMemcpyAsync(bqkv, bq, D * 4, hipMemcpyDeviceToDevice, stream);
  hipMemcpyAsync(bqkv + D, bk, D * 4, hipMemcpyDeviceToDevice, stream);
  hipMemcpyAsync(bqkv + 2 * D, bv, D * 4, hipMemcpyDeviceToDevice, stream);

  // QKV projection: (49152 x 1024) @ (1024 x 3072)
  hipLaunchKernelGGL((gemm_bt<false>), dim3((M / 128) * (3 * D / 128)), dim3(256), 0, stream,
                     (const __hip_bfloat16*)Xb, (const __hip_bfloat16*)Wqkv, bqkv,
                     (void*)QKV, M, 3 * D, D);
  // ctx projection: (16384 x 1024) @ (1024 x 1024)
  hipLaunchKernelGGL((gemm_bt<false>), dim3((Mc / 128) * (D / 128)), dim3(256), 0, stream,
                     (const __hip_bfloat16*)Cin, (const __hip_bfloat16*)Wcb, bc,
                     (void*)Cpr, Mc, D, D);
  // attention (writes into Xb, which is dead after the QKV GEMM)
  hipLaunchKernelGGL(attn_kernel, dim3(BB * HH / 4), dim3(256), 0, stream, QKV, Cpr, Xb);
  // output projection -> fp32 d_out with bias
  hipLaunchKernelGGL((gemm_bt<true>), dim3((M / 128) * (D / 128)), dim3(256), 0, stream,
                     (const __hip_bfloat16*)Xb, (const __hip_bfloat16*)Wob, bo,
                     d_out, M, D, D);
}

// Round 2
// 751.873 us; speedup vs baseline: 1.2239x; 1.2239x over previous
//
#include <hip/hip_runtime.h>
#include <hip/hip_bf16.h>

#define BB 16384
#define KK 3
#define DD 1024
#define HH 16

typedef __attribute__((ext_vector_type(8))) short bf16x8;
typedef __attribute__((ext_vector_type(4))) float f32x4;
typedef unsigned int u32;

__device__ __forceinline__ void load_lds16(const void* g, void* l) {
  __builtin_amdgcn_global_load_lds(
      (const __attribute__((address_space(1))) u32*)g,
      (__attribute__((address_space(3))) u32*)l,
      16, 0, 0);
}

__device__ __forceinline__ unsigned short f2bf(float f) {
  __hip_bfloat16 h = __float2bfloat16(f);
  unsigned short u;
  __builtin_memcpy(&u, &h, 2);
  return u;
}

__device__ __forceinline__ float bf2f(unsigned short u) {
  union { float f; u32 i; } cv;
  cv.i = ((u32)u) << 16;
  return cv.f;
}

// ---------------------------------------------------------------- cast fp32 -> bf16
__global__ void cast_f32_bf16(const float* __restrict__ in,
                              unsigned short* __restrict__ out, int n4) {
  int stride = gridDim.x * blockDim.x;
  for (int i = blockIdx.x * blockDim.x + threadIdx.x; i < n4; i += stride) {
    float4 v = ((const float4*)in)[i];
    ushort4 o;
    o.x = f2bf(v.x);
    o.y = f2bf(v.y);
    o.z = f2bf(v.z);
    o.w = f2bf(v.w);
    ((ushort4*)out)[i] = o;
  }
}

// ---------------------------------------------------------------- GEMM: C = A @ Bt^T + bias
// 256x256 tile, BK=32, 512 threads = 8 waves (2M x 4N), per-wave 128x64 output.
// 4-deep circular LDS pipeline (4 x 32KB), counted vmcnt (12 steady state),
// raw s_barrier (no compiler vmcnt(0) drain), T2 chunk-XOR swizzle applied on
// BOTH the pre-swizzled global source and the ds_read address (LDS dest linear,
// as global_load_lds requires). T5 setprio around the MFMA cluster.
// Requires K % 32 == 0 and K/32 >= 4. Grids here are all % 8 == 0 (XCD swizzle).
template <bool OUT_F32>
__global__ __launch_bounds__(512, 2)
void gemm256(const __hip_bfloat16* __restrict__ A,
             const __hip_bfloat16* __restrict__ Bt,
             const float* __restrict__ bias,
             void* __restrict__ Cout,
             int M, int N, int K) {
  __shared__ char lds[131072];

  const int nTn = N >> 8;
  const int nwg = (M >> 8) * nTn;
  int bid = blockIdx.x;
  bid = (bid & 7) * (nwg >> 3) + (bid >> 3);  // bijective XCD swizzle (nwg%8==0)
  const int tm = bid / nTn;
  const int tn = bid % nTn;

  const int tid = threadIdx.x;
  const int l = tid & 63;
  const int w = tid >> 6;
  const int wm = w >> 2;   // 0..1
  const int wn = w & 3;    // 0..3
  const int l15 = l & 15;
  const int g = l >> 4;
  const int csel = (l15 >> 2) & 3;

  // --- staging geometry (per thread, one 16B slice per instruction) ---
  const int srow = tid >> 2;                   // 0..127
  const int schunk = tid & 3;                  // 16B chunk within 64B k-row
  const int scsrc = schunk ^ ((tid >> 4) & 3); // pre-swizzled source chunk
  const size_t strideK = (size_t)K * 2;        // row stride in bytes
  const char* Ab = (const char*)A + (size_t)tm * 256 * strideK;
  const char* Bb = (const char*)Bt + (size_t)tn * 256 * strideK;
  const size_t sgoff0 = (size_t)srow * strideK + (size_t)(scsrc << 4);
  const size_t sgoff1 = sgoff0 + 128 * strideK;
  const int sldst = tid << 4;                  // linear LDS dest (row*64+chunk*16)

  // --- read bases (byte offsets inside one 32KB buffer) ---
  const int laneA = (((wm << 7) + l15) << 6) + ((g ^ csel) << 4);
  const int laneB = 16384 + (((wn << 6) + l15) << 6) + ((g ^ csel) << 4);

  f32x4 acc[8][4] = {};

  const int nkt = K >> 5;

#define STAGE(T)                                                         \
  {                                                                      \
    char* sb_ = lds + (((T) & 3) << 15);                                 \
    const char* gA_ = Ab + (size_t)((T) << 6);                           \
    const char* gB_ = Bb + (size_t)((T) << 6);                           \
    load_lds16(gA_ + sgoff0, sb_ + sldst);                               \
    load_lds16(gA_ + sgoff1, sb_ + 8192 + sldst);                        \
    load_lds16(gB_ + sgoff0, sb_ + 16384 + sldst);                       \
    load_lds16(gB_ + sgoff1, sb_ + 24576 + sldst);                       \
  }

#define COMPUTE(T)                                                       \
  {                                                                      \
    const char* sb_ = lds + (((T) & 3) << 15);                           \
    asm volatile("" ::: "memory");                                       \
    bf16x8 af[8], bfr[4];                                                \
    _Pragma("unroll") for (int m_ = 0; m_ < 8; ++m_)                     \
        af[m_] = *(const bf16x8*)(sb_ + laneA + (m_ << 10));             \
    _Pragma("unroll") for (int n_ = 0; n_ < 4; ++n_)                     \
        bfr[n_] = *(const bf16x8*)(sb_ + laneB + (n_ << 10));            \
    __builtin_amdgcn_s_setprio(1);                                      \
    _Pragma("unroll") for (int m_ = 0; m_ < 8; ++m_)                     \
        _Pragma("unroll") for (int n_ = 0; n_ < 4; ++n_)                 \
            acc[m_][n_] = __builtin_amdgcn_mfma_f32_16x16x32_bf16(       \
                af[m_], bfr[n_], acc[m_][n_], 0, 0, 0);                  \
    __builtin_amdgcn_s_setprio(0);                                      \
    asm volatile("" ::: "memory");                                       \
  }

  STAGE(0);
  STAGE(1);
  STAGE(2);
  for (int t = 0; t < nkt - 3; ++t) {
    STAGE(t + 3);
    asm volatile("s_waitcnt vmcnt(12)" ::: "memory");
    __builtin_amdgcn_s_barrier();
    COMPUTE(t);
    __builtin_amdgcn_s_barrier();
  }
  {
    asm volatile("s_waitcnt vmcnt(8)" ::: "memory");
    __builtin_amdgcn_s_barrier();
    COMPUTE(nkt - 3);
    __builtin_amdgcn_s_barrier();
  }
  {
    asm volatile("s_waitcnt vmcnt(4)" ::: "memory");
    __builtin_amdgcn_s_barrier();
    COMPUTE(nkt - 2);
    __builtin_amdgcn_s_barrier();
  }
  {
    asm volatile("s_waitcnt vmcnt(0)" ::: "memory");
    __builtin_amdgcn_s_barrier();
    COMPUTE(nkt - 1);
  }
#undef STAGE
#undef COMPUTE

  // epilogue: C/D layout col = lane&15, row = (lane>>4)*4 + reg  [m89-verified]
  const int cbase = tn * 256 + (wn << 6) + l15;
  float b4[4];
#pragma unroll
  for (int n = 0; n < 4; ++n) b4[n] = bias[cbase + (n << 4)];
  const size_t rbase = (size_t)tm * 256 + (wm << 7) + ((l >> 4) << 2);
#pragma unroll
  for (int m = 0; m < 8; ++m) {
#pragma unroll
    for (int j = 0; j < 4; ++j) {
      const size_t row = rbase + (m << 4) + j;
#pragma unroll
      for (int n = 0; n < 4; ++n) {
        const int col = cbase + (n << 4);
        float v = acc[m][n][j] + b4[n];
        if (OUT_F32)
          ((float*)Cout)[row * N + col] = v;
        else
          ((unsigned short*)Cout)[row * N + col] = f2bf(v);
      }
    }
  }
}

// ---------------------------------------------------------------- attention
// One wave per (b,h). lane = d (head dim 64). K=3 queries/keys.
__global__ __launch_bounds__(256)
void attn_kernel(const unsigned short* __restrict__ QKV,  // (B*3) x 3072
                 const unsigned short* __restrict__ Cp,   // B x 1024
                 unsigned short* __restrict__ Out) {      // (B*3) x 1024
  const int wid = (blockIdx.x * 256 + threadIdx.x) >> 6;
  const int l = threadIdx.x & 63;
  const int b = wid >> 4;   // H = 16
  const int h = wid & 15;

  const size_t qbase = (size_t)b * 3 * 3072 + h * 64 + l;
  const float c = bf2f(Cp[(size_t)b * 1024 + h * 64 + l]);

  float q[3], kc[3], vc[3];
#pragma unroll
  for (int i = 0; i < 3; ++i) {
    q[i]  = bf2f(QKV[qbase + (size_t)i * 3072]);
    kc[i] = bf2f(QKV[qbase + (size_t)i * 3072 + 1024]) * c;
    vc[i] = bf2f(QKV[qbase + (size_t)i * 3072 + 2048]) * c;
  }

  float s[9];
#pragma unroll
  for (int i = 0; i < 3; ++i)
#pragma unroll
    for (int j = 0; j < 3; ++j)
      s[i * 3 + j] = q[i] * kc[j];

#pragma unroll
  for (int off = 32; off > 0; off >>= 1)
#pragma unroll
    for (int e = 0; e < 9; ++e)
      s[e] += __shfl_xor(s[e], off, 64);

  const float scale = 0.125f;  // 1/sqrt(64)
  float o[3];
#pragma unroll
  for (int i = 0; i < 3; ++i) {
    float s0 = s[i * 3 + 0] * scale;
    float s1 = s[i * 3 + 1] * scale;
    float s2 = s[i * 3 + 2] * scale;
    float m = fmaxf(fmaxf(s0, s1), s2);
    float p0 = expf(s0 - m), p1 = expf(s1 - m), p2 = expf(s2 - m);
    float inv = 1.0f / (p0 + p1 + p2);
    o[i] = (p0 * vc[0] + p1 * vc[1] + p2 * vc[2]) * inv;
  }
#pragma unroll
  for (int i = 0; i < 3; ++i)
    Out[(size_t)(b * 3 + i) * 1024 + h * 64 + l] = f2bf(o[i]);
}

// ---------------------------------------------------------------- launch
extern "C" void kernel_launch(void* const* d_in, const int* in_sizes, int n_in,
                              void* d_out, int out_size, void* d_ws, size_t ws_size,
                              hipStream_t stream) {
  const float* tokens = (const float*)d_in[0];
  const float* ctx    = (const float*)d_in[1];
  const float* Wq     = (const float*)d_in[2];
  const float* bq     = (const float*)d_in[3];
  const float* Wk     = (const float*)d_in[4];
  const float* bk     = (const float*)d_in[5];
  const float* Wv     = (const float*)d_in[6];
  const float* bv     = (const float*)d_in[7];
  const float* Wc     = (const float*)d_in[8];
  const float* bc     = (const float*)d_in[9];
  const float* Wo     = (const float*)d_in[10];
  const float* bo     = (const float*)d_in[11];

  const int M  = BB * KK;   // 49152 token rows
  const int Mc = BB;        // 16384 ctx rows
  const int D  = DD;        // 1024

  char* p = (char*)d_ws;
  auto carve = [&](size_t bytes) {
    char* r = p;
    p += (bytes + 255) & ~(size_t)255;
    return r;
  };
  unsigned short* Xb   = (unsigned short*)carve((size_t)M * D * 2);  // tokens bf16; reused as attn out
  unsigned short* Cin  = (unsigned short*)carve((size_t)Mc * D * 2);
  unsigned short* Wqkv = (unsigned short*)carve((size_t)3 * D * D * 2);
  unsigned short* Wcb  = (unsigned short*)carve((size_t)D * D * 2);
  unsigned short* Wob  = (unsigned short*)carve((size_t)D * D * 2);
  float*          bqkv = (float*)carve((size_t)3 * D * 4);
  unsigned short* QKV  = (unsigned short*)carve((size_t)M * 3 * D * 2);
  unsigned short* Cpr  = (unsigned short*)carve((size_t)Mc * D * 2);

  hipLaunchKernelGGL(cast_f32_bf16, dim3(4096), dim3(256), 0, stream, tokens, Xb, M * D / 4);
  hipLaunchKernelGGL(cast_f32_bf16, dim3(2048), dim3(256), 0, stream, ctx, Cin, Mc * D / 4);
  hipLaunchKernelGGL(cast_f32_bf16, dim3(512), dim3(256), 0, stream, Wq, Wqkv, D * D / 4);
  hipLaunchKernelGGL(cast_f32_bf16, dim3(512), dim3(256), 0, stream, Wk, Wqkv + D * D, D * D / 4);
  hipLaunchKernelGGL(cast_f32_bf16, dim3(512), dim3(256), 0, stream, Wv, Wqkv + 2 * D * D, D * D / 4);
  hipLaunchKernelGGL(cast_f32_bf16, dim3(512), dim3(256), 0, stream, Wc, Wcb, D * D / 4);
  hipLaunchKernelGGL(cast_f32_bf16, dim3(512), dim3(256), 0, stream, Wo, Wob, D * D / 4);
  hipMemcpyAsync(bqkv, bq, D * 4, hipMemcpyDeviceToDevice, stream);
  hipMemcpyAsync(bqkv + D, bk, D * 4, hipMemcpyDeviceToDevice, stream);
  hipMemcpyAsync(bqkv + 2 * D, bv, D * 4, hipMemcpyDeviceToDevice, stream);

  // QKV projection: (49152 x 1024) @ (1024 x 3072) -> 192*12 = 2304 blocks
  hipLaunchKernelGGL((gemm256<false>), dim3((M / 256) * (3 * D / 256)), dim3(512), 0, stream,
                     (const __hip_bfloat16*)Xb, (const __hip_bfloat16*)Wqkv, bqkv,
                     (void*)QKV, M, 3 * D, D);
  // ctx projection: (16384 x 1024) @ (1024 x 1024) -> 64*4 = 256 blocks
  hipLaunchKernelGGL((gemm256<false>), dim3((Mc / 256) * (D / 256)), dim3(512), 0, stream,
                     (const __hip_bfloat16*)Cin, (const __hip_bfloat16*)Wcb, bc,
                     (void*)Cpr, Mc, D, D);
  // attention (writes into Xb, dead after the QKV GEMM)
  hipLaunchKernelGGL(attn_kernel, dim3(BB * HH / 4), dim3(256), 0, stream, QKV, Cpr, Xb);
  // output projection -> fp32 d_out with bias: 192*4 = 768 blocks
  hipLaunchKernelGGL((gemm256<true>), dim3((M / 256) * (D / 256)), dim3(512), 0, stream,
                     (const __hip_bfloat16*)Xb, (const __hip_bfloat16*)Wob, bo,
                     d_out, M, D, D);
}

// Round 3
// 679.303 us; speedup vs baseline: 1.3547x; 1.1068x over previous
//
#include <hip/hip_runtime.h>
#include <hip/hip_bf16.h>

#define BB 16384
#define KK 3
#define DD 1024
#define HH 16

typedef __attribute__((ext_vector_type(8))) short bf16x8;
typedef __attribute__((ext_vector_type(4))) float f32x4;
typedef unsigned int u32;

__device__ __forceinline__ void load_lds16(const void* g, void* l) {
  __builtin_amdgcn_global_load_lds(
      (const __attribute__((address_space(1))) u32*)g,
      (__attribute__((address_space(3))) u32*)l,
      16, 0, 0);
}

__device__ __forceinline__ unsigned short f2bf(float f) {
  __hip_bfloat16 h = __float2bfloat16(f);
  unsigned short u;
  __builtin_memcpy(&u, &h, 2);
  return u;
}

__device__ __forceinline__ float bf2f(unsigned short u) {
  union { float f; u32 i; } cv;
  cv.i = ((u32)u) << 16;
  return cv.f;
}

// ---------------------------------------------------------------- cast fp32 -> bf16
__global__ void cast_f32_bf16(const float* __restrict__ in,
                              unsigned short* __restrict__ out, int n4) {
  int stride = gridDim.x * blockDim.x;
  for (int i = blockIdx.x * blockDim.x + threadIdx.x; i < n4; i += stride) {
    float4 v = ((const float4*)in)[i];
    ushort4 o;
    o.x = f2bf(v.x);
    o.y = f2bf(v.y);
    o.z = f2bf(v.z);
    o.w = f2bf(v.w);
    ((ushort4*)out)[i] = o;
  }
}

// ---------------------------------------------------------------- GEMM: C = A @ Bt^T + bias
// 256x256 tile, BK=64, 512 threads = 8 waves (2M x 4N), per-wave 128x64.
// Double-buffered LDS (2 x 64KB). Per K-tile 4 phases:
//   {vmcnt(8); bar; reads k0; MFMA m0-3 k0; MFMA m4-7 k0; reads k1;
//    MFMA m0-3 k1; lgkm(0); bar; STAGE(kt+2); MFMA m4-7 k1}
// LDS layout per matrix-half: [128 rows][128B], physical chunk = logical ^ (row&7)
// (both-sides swizzle: pre-swizzled global source, swizzled ds_read; dest linear).
// Counted vmcnt(8) in steady state (T4); stages issue only after the block-wide
// lgkmcnt(0) barrier, so in-flight LDS writes cannot clobber pending ds_reads.
template <bool OUT_F32>
__global__ __launch_bounds__(512, 2)
void gemm256(const __hip_bfloat16* __restrict__ A,
             const __hip_bfloat16* __restrict__ Bt,
             const float* __restrict__ bias,
             void* __restrict__ Cout,
             int M, int N, int K) {
  __shared__ __align__(128) char lds[131072];

  const int nTn = N >> 8;
  const int nwg = (M >> 8) * nTn;
  int bid = blockIdx.x;
  bid = (bid & 7) * (nwg >> 3) + (bid >> 3);  // bijective XCD swizzle (nwg%8==0)
  const int tm = bid / nTn;
  const int tn = bid % nTn;

  const int tid = threadIdx.x;
  const int l = tid & 63;
  const int w = tid >> 6;
  const int wm = w >> 2;   // 0..1
  const int wn = w & 3;    // 0..3
  const int l15 = l & 15;
  const int g = l >> 4;
  const int l7 = l15 & 7;

  // fragment-read constants
  const int rA = l15 << 7;                    // row byte within [*][128B]
  const int cs0 = ((g ^ l7) << 4);            // k-half 0 swizzled chunk byte
  const int cs1 = (((4 | g) ^ l7) << 4);      // k-half 1

  // staging constants (per thread: 8 x 16B per tile)
  const size_t strideK = (size_t)K * 2;
  const char* Ab = (const char*)A + (size_t)tm * 256 * strideK;
  const char* Bb = (const char*)Bt + (size_t)tn * 256 * strideK;
  const int sld = tid << 4;                                   // linear LDS dst
  const int lch = (((tid & 7) ^ ((tid >> 3) & 7)) << 4);      // pre-swz src chunk
  const size_t so0 = (size_t)(tid >> 3) * strideK + lch;      // rows 0-63
  const size_t so1 = so0 + (size_t)64 * strideK;              // rows 64-127
  const size_t h1 = (size_t)128 * strideK;                    // rows 128-255

  f32x4 acc[8][4] = {};
  const int nkt = K >> 6;  // BK = 64

#define STAGE(T)                                                          \
  {                                                                       \
    char* bb = lds + (((T) & 1) << 16);                                   \
    const char* ga = Ab + ((size_t)(T) << 7);                             \
    const char* gb = Bb + ((size_t)(T) << 7);                             \
    load_lds16(ga + so0, bb + sld);                                       \
    load_lds16(ga + so1, bb + 8192 + sld);                                \
    load_lds16(ga + h1 + so0, bb + 16384 + sld);                          \
    load_lds16(ga + h1 + so1, bb + 16384 + 8192 + sld);                   \
    load_lds16(gb + so0, bb + 32768 + sld);                               \
    load_lds16(gb + so1, bb + 32768 + 8192 + sld);                        \
    load_lds16(gb + h1 + so0, bb + 49152 + sld);                          \
    load_lds16(gb + h1 + so1, bb + 49152 + 8192 + sld);                   \
  }

#define MFMA_BLK(M0)                                                      \
  __builtin_amdgcn_s_setprio(1);                                          \
  _Pragma("unroll") for (int mm = 0; mm < 4; ++mm)                        \
      _Pragma("unroll") for (int nn = 0; nn < 4; ++nn)                    \
          acc[(M0) + mm][nn] = __builtin_amdgcn_mfma_f32_16x16x32_bf16(   \
              af[(M0) + mm], bfr[nn], acc[(M0) + mm][nn], 0, 0, 0);       \
  __builtin_amdgcn_s_setprio(0);

  STAGE(0);
  STAGE(1);

  for (int kt = 0; kt < nkt; ++kt) {
    const char* Ah = lds + ((kt & 1) << 16) + (wm << 14);
    const char* Bh = lds + ((kt & 1) << 16) + 32768 + (wn << 13);

    if (kt < nkt - 1)
      asm volatile("s_waitcnt vmcnt(8)" ::: "memory");
    else
      asm volatile("s_waitcnt vmcnt(0)" ::: "memory");
    __builtin_amdgcn_s_barrier();
    asm volatile("" ::: "memory");

    bf16x8 af[8], bfr[4];
    // ---- k-half 0 reads
#pragma unroll
    for (int m = 0; m < 8; ++m)
      af[m] = *(const bf16x8*)(Ah + (m << 11) + rA + cs0);
#pragma unroll
    for (int n = 0; n < 4; ++n)
      bfr[n] = *(const bf16x8*)(Bh + (n << 11) + rA + cs0);

    MFMA_BLK(0)   // phase 0: m0-3 x k0
    MFMA_BLK(4)   // phase 1: m4-7 x k0

    // ---- k-half 1 reads (reuse regs)
#pragma unroll
    for (int m = 0; m < 8; ++m)
      af[m] = *(const bf16x8*)(Ah + (m << 11) + rA + cs1);
#pragma unroll
    for (int n = 0; n < 4; ++n)
      bfr[n] = *(const bf16x8*)(Bh + (n << 11) + rA + cs1);

    MFMA_BLK(0)   // phase 2: m0-3 x k1

    asm volatile("s_waitcnt lgkmcnt(0)" ::: "memory");
    __builtin_amdgcn_sched_barrier(0);
    __builtin_amdgcn_s_barrier();   // all waves done reading buf (kt&1)
    asm volatile("" ::: "memory");

    if (kt + 2 < nkt) STAGE(kt + 2);  // safe: every read of this buf completed

    MFMA_BLK(4)   // phase 3: m4-7 x k1 (overlaps stage issue)
  }
#undef STAGE
#undef MFMA_BLK

  // epilogue: C/D layout col = lane&15, row = (lane>>4)*4 + reg  [m89-verified]
  const int cbase = tn * 256 + (wn << 6) + l15;
  float b4[4];
#pragma unroll
  for (int n = 0; n < 4; ++n) b4[n] = bias[cbase + (n << 4)];
  const size_t rbase = (size_t)tm * 256 + (wm << 7) + ((l >> 4) << 2);
#pragma unroll
  for (int m = 0; m < 8; ++m) {
#pragma unroll
    for (int j = 0; j < 4; ++j) {
      const size_t row = rbase + (m << 4) + j;
#pragma unroll
      for (int n = 0; n < 4; ++n) {
        const int col = cbase + (n << 4);
        float v = acc[m][n][j] + b4[n];
        if (OUT_F32)
          ((float*)Cout)[row * N + col] = v;
        else
          ((unsigned short*)Cout)[row * N + col] = f2bf(v);
      }
    }
  }
}

// ---------------------------------------------------------------- attention
// 16 lanes per (b,h); lane x handles dims 4x..4x+3 via ushort4 (8B/lane loads).
__global__ __launch_bounds__(256)
void attn_kernel(const unsigned short* __restrict__ QKV,  // (B*3) x 3072
                 const unsigned short* __restrict__ Cp,   // B x 1024
                 unsigned short* __restrict__ Out) {      // (B*3) x 1024
  const int t = threadIdx.x;
  const int grp = (blockIdx.x << 4) + (t >> 4);
  const int x = t & 15;
  const int b = grp >> 4;   // H = 16
  const int h = grp & 15;

  const size_t col = (size_t)h * 64 + (x << 2);
  const size_t qbase = (size_t)b * 3 * 3072 + col;

  ushort4 cu = *(const ushort4*)&Cp[(size_t)b * 1024 + col];
  float c[4] = {bf2f(cu.x), bf2f(cu.y), bf2f(cu.z), bf2f(cu.w)};

  float q[3][4], kc[3][4], vc[3][4];
#pragma unroll
  for (int i = 0; i < 3; ++i) {
    ushort4 qu = *(const ushort4*)&QKV[qbase + (size_t)i * 3072];
    ushort4 ku = *(const ushort4*)&QKV[qbase + (size_t)i * 3072 + 1024];
    ushort4 vu = *(const ushort4*)&QKV[qbase + (size_t)i * 3072 + 2048];
    q[i][0] = bf2f(qu.x); q[i][1] = bf2f(qu.y); q[i][2] = bf2f(qu.z); q[i][3] = bf2f(qu.w);
    kc[i][0] = bf2f(ku.x) * c[0]; kc[i][1] = bf2f(ku.y) * c[1];
    kc[i][2] = bf2f(ku.z) * c[2]; kc[i][3] = bf2f(ku.w) * c[3];
    vc[i][0] = bf2f(vu.x) * c[0]; vc[i][1] = bf2f(vu.y) * c[1];
    vc[i][2] = bf2f(vu.z) * c[2]; vc[i][3] = bf2f(vu.w) * c[3];
  }

  float s[9];
#pragma unroll
  for (int i = 0; i < 3; ++i)
#pragma unroll
    for (int j = 0; j < 3; ++j)
      s[i * 3 + j] = q[i][0] * kc[j][0] + q[i][1] * kc[j][1] +
                     q[i][2] * kc[j][2] + q[i][3] * kc[j][3];

  // reduce across the 16-lane group (head dim)
#pragma unroll
  for (int off = 8; off > 0; off >>= 1)
#pragma unroll
    for (int e = 0; e < 9; ++e)
      s[e] += __shfl_xor(s[e], off, 64);

  const float scale = 0.125f;  // 1/sqrt(64)
#pragma unroll
  for (int i = 0; i < 3; ++i) {
    float s0 = s[i * 3 + 0] * scale;
    float s1 = s[i * 3 + 1] * scale;
    float s2 = s[i * 3 + 2] * scale;
    float m = fmaxf(fmaxf(s0, s1), s2);
    float p0 = expf(s0 - m), p1 = expf(s1 - m), p2 = expf(s2 - m);
    float inv = 1.0f / (p0 + p1 + p2);
    ushort4 o;
    o.x = f2bf((p0 * vc[0][0] + p1 * vc[1][0] + p2 * vc[2][0]) * inv);
    o.y = f2bf((p0 * vc[0][1] + p1 * vc[1][1] + p2 * vc[2][1]) * inv);
    o.z = f2bf((p0 * vc[0][2] + p1 * vc[1][2] + p2 * vc[2][2]) * inv);
    o.w = f2bf((p0 * vc[0][3] + p1 * vc[1][3] + p2 * vc[2][3]) * inv);
    *(ushort4*)&Out[(size_t)(b * 3 + i) * 1024 + col] = o;
  }
}

// ---------------------------------------------------------------- launch
extern "C" void kernel_launch(void* const* d_in, const int* in_sizes, int n_in,
                              void* d_out, int out_size, void* d_ws, size_t ws_size,
                              hipStream_t stream) {
  const float* tokens = (const float*)d_in[0];
  const float* ctx    = (const float*)d_in[1];
  const float* Wq     = (const float*)d_in[2];
  const float* bq     = (const float*)d_in[3];
  const float* Wk     = (const float*)d_in[4];
  const float* bk     = (const float*)d_in[5];
  const float* Wv     = (const float*)d_in[6];
  const float* bv     = (const float*)d_in[7];
  const float* Wc     = (const float*)d_in[8];
  const float* bc     = (const float*)d_in[9];
  const float* Wo     = (const float*)d_in[10];
  const float* bo     = (const float*)d_in[11];

  const int M  = BB * KK;   // 49152 token rows
  const int Mc = BB;        // 16384 ctx rows
  const int D  = DD;        // 1024

  char* p = (char*)d_ws;
  auto carve = [&](size_t bytes) {
    char* r = p;
    p += (bytes + 255) & ~(size_t)255;
    return r;
  };
  unsigned short* Xb   = (unsigned short*)carve((size_t)M * D * 2);  // tokens bf16; reused as attn out
  unsigned short* Cin  = (unsigned short*)carve((size_t)Mc * D * 2);
  unsigned short* Wqkv = (unsigned short*)carve((size_t)3 * D * D * 2);
  unsigned short* Wcb  = (unsigned short*)carve((size_t)D * D * 2);
  unsigned short* Wob  = (unsigned short*)carve((size_t)D * D * 2);
  float*          bqkv = (float*)carve((size_t)3 * D * 4);
  unsigned short* QKV  = (unsigned short*)carve((size_t)M * 3 * D * 2);
  unsigned short* Cpr  = (unsigned short*)carve((size_t)Mc * D * 2);

  hipLaunchKernelGGL(cast_f32_bf16, dim3(4096), dim3(256), 0, stream, tokens, Xb, M * D / 4);
  hipLaunchKernelGGL(cast_f32_bf16, dim3(2048), dim3(256), 0, stream, ctx, Cin, Mc * D / 4);
  hipLaunchKernelGGL(cast_f32_bf16, dim3(512), dim3(256), 0, stream, Wq, Wqkv, D * D / 4);
  hipLaunchKernelGGL(cast_f32_bf16, dim3(512), dim3(256), 0, stream, Wk, Wqkv + D * D, D * D / 4);
  hipLaunchKernelGGL(cast_f32_bf16, dim3(512), dim3(256), 0, stream, Wv, Wqkv + 2 * D * D, D * D / 4);
  hipLaunchKernelGGL(cast_f32_bf16, dim3(512), dim3(256), 0, stream, Wc, Wcb, D * D / 4);
  hipLaunchKernelGGL(cast_f32_bf16, dim3(512), dim3(256), 0, stream, Wo, Wob, D * D / 4);
  hipMemcpyAsync(bqkv, bq, D * 4, hipMemcpyDeviceToDevice, stream);
  hipMemcpyAsync(bqkv + D, bk, D * 4, hipMemcpyDeviceToDevice, stream);
  hipMemcpyAsync(bqkv + 2 * D, bv, D * 4, hipMemcpyDeviceToDevice, stream);

  // QKV projection: (49152 x 1024) @ (1024 x 3072) -> 192*12 = 2304 blocks
  hipLaunchKernelGGL((gemm256<false>), dim3((M / 256) * (3 * D / 256)), dim3(512), 0, stream,
                     (const __hip_bfloat16*)Xb, (const __hip_bfloat16*)Wqkv, bqkv,
                     (void*)QKV, M, 3 * D, D);
  // ctx projection: (16384 x 1024) @ (1024 x 1024) -> 64*4 = 256 blocks
  hipLaunchKernelGGL((gemm256<false>), dim3((Mc / 256) * (D / 256)), dim3(512), 0, stream,
                     (const __hip_bfloat16*)Cin, (const __hip_bfloat16*)Wcb, bc,
                     (void*)Cpr, Mc, D, D);
  // attention (writes into Xb, dead after the QKV GEMM)
  hipLaunchKernelGGL(attn_kernel, dim3(BB * HH / 16), dim3(256), 0, stream, QKV, Cpr, Xb);
  // output projection -> fp32 d_out with bias: 192*4 = 768 blocks
  hipLaunchKernelGGL((gemm256<true>), dim3((M / 256) * (D / 256)), dim3(512), 0, stream,
                     (const __hip_bfloat16*)Xb, (const __hip_bfloat16*)Wob, bo,
                     d_out, M, D, D);
}

// Round 4
// 666.383 us; speedup vs baseline: 1.3809x; 1.0194x over previous
//
#include <hip/hip_runtime.h>
#include <hip/hip_bf16.h>

#define BB 16384
#define KK 3
#define DD 1024
#define HH 16

typedef __attribute__((ext_vector_type(8))) short bf16x8;
typedef __attribute__((ext_vector_type(4))) float f32x4;
typedef unsigned int u32;

__device__ __forceinline__ void load_lds16(const void* g, void* l) {
  __builtin_amdgcn_global_load_lds(
      (const __attribute__((address_space(1))) u32*)g,
      (__attribute__((address_space(3))) u32*)l,
      16, 0, 0);
}

__device__ __forceinline__ unsigned short f2bf(float f) {
  __hip_bfloat16 h = __float2bfloat16(f);
  unsigned short u;
  __builtin_memcpy(&u, &h, 2);
  return u;
}

__device__ __forceinline__ float bf2f(unsigned short u) {
  union { float f; u32 i; } cv;
  cv.i = ((u32)u) << 16;
  return cv.f;
}

// ---------------------------------------------------------------- cast fp32 -> bf16
__global__ void cast_f32_bf16(const float* __restrict__ in,
                              unsigned short* __restrict__ out, int n4) {
  int stride = gridDim.x * blockDim.x;
  for (int i = blockIdx.x * blockDim.x + threadIdx.x; i < n4; i += stride) {
    float4 v = ((const float4*)in)[i];
    ushort4 o;
    o.x = f2bf(v.x);
    o.y = f2bf(v.y);
    o.z = f2bf(v.z);
    o.w = f2bf(v.w);
    ((ushort4*)out)[i] = o;
  }
}

// ---------------------------------------------------------------- GEMM: C = A @ Bt^T + bias
// m201-style 8-phase schedule at BK=32 granularity.
// 256x256 tile, 512 threads = 8 waves (2M x 4N), per-wave 128x64 output.
// 4-slot LDS ring (4 x 32KB). Per K-tile, 2 phases:
//   P0: {8 ds_read (B n0-3 + A m0-3) | 2 gload_lds(A, kt+3) | sbar | lgkm0 |
//        setprio1 16 MFMA setprio0 | sbar}
//   P1: {4 ds_read (A m4-7) | 2 gload_lds(B, kt+3) | vmcnt(8/4/0 for kt+1) |
//        sbar | lgkm0 | setprio1 16 MFMA setprio0 | sbar}
// Slot layout: A [128 lines][128B] (line = row&127, logical chunk q = (row>>7)*4
// + kchunk, physical p = q ^ (line&7)), B same at +16KB. Stage targets slot
// (kt+3)&3 = (kt-1)&3 whose reads completed a full tile ago (barrier-ordered).
// vmcnt(8) steady state (3 tiles in flight, ~900cyc HBM latency covered).
template <bool OUT_F32>
__global__ __launch_bounds__(512, 2)
void gemm256(const __hip_bfloat16* __restrict__ A,
             const __hip_bfloat16* __restrict__ Bt,
             const float* __restrict__ bias,
             void* __restrict__ Cout,
             int M, int N, int K) {
  __shared__ __align__(128) char lds[131072];

  const int nTn = N >> 8;
  const int nwg = (M >> 8) * nTn;
  int bid = blockIdx.x;
  bid = (bid & 7) * (nwg >> 3) + (bid >> 3);  // bijective XCD swizzle (nwg%8==0)
  const int tm = bid / nTn;
  const int tn = bid % nTn;

  const int tid = threadIdx.x;
  const int l = tid & 63;
  const int w = tid >> 6;
  const int wm = w >> 2;   // 0..1
  const int wn = w & 3;    // 0..3
  const int l15 = l & 15;
  const int g = l >> 4;    // k-chunk group 0..3
  const int l7 = l15 & 7;

  // fragment-read byte offsets inside a slot
  const int aBase = (l15 << 7) + (((wm << 2) + g) ^ l7) * 16;
  const int bBase = 16384 + ((((wn & 1) << 6) + l15) << 7) +
                    ((((wn >> 1) << 2) + g) ^ l7) * 16;

  // staging geometry (per thread: 4 x 16B per tile; dest linear, source
  // pre-swizzled so that physical chunk p = q ^ (line&7))
  const size_t strideK = (size_t)K * 2;
  const char* Ab = (const char*)A + (size_t)tm * 256 * strideK;
  const char* Bb = (const char*)Bt + (size_t)tn * 256 * strideK;
  const int q = (tid & 7) ^ ((tid >> 3) & 7);
  const size_t g0 = (size_t)((q >> 2) * 128 + (tid >> 3)) * strideK + (q & 3) * 16;
  const size_t g1 = g0 + (size_t)64 * strideK;
  const int sld = tid << 4;

  f32x4 acc[8][4] = {};
  const int nkt = K >> 5;  // BK = 32

#define STAGE_A(T)                                                        \
  {                                                                       \
    char* sb = lds + (((T) & 3) << 15);                                   \
    const char* ga = Ab + ((size_t)(T) << 6);                             \
    load_lds16(ga + g0, sb + sld);                                        \
    load_lds16(ga + g1, sb + 8192 + sld);                                 \
  }
#define STAGE_B(T)                                                        \
  {                                                                       \
    char* sb = lds + (((T) & 3) << 15);                                   \
    const char* gb = Bb + ((size_t)(T) << 6);                             \
    load_lds16(gb + g0, sb + 16384 + sld);                                \
    load_lds16(gb + g1, sb + 24576 + sld);                                \
  }
#define MFMA_HALF(H)                                                      \
  __builtin_amdgcn_s_setprio(1);                                          \
  _Pragma("unroll") for (int mm = 0; mm < 4; ++mm)                        \
      _Pragma("unroll") for (int nn = 0; nn < 4; ++nn)                    \
          acc[(H) + mm][nn] = __builtin_amdgcn_mfma_f32_16x16x32_bf16(    \
              af[mm], bfr[nn], acc[(H) + mm][nn], 0, 0, 0);               \
  __builtin_amdgcn_s_setprio(0);

  // prologue: stage tiles 0,1,2; drain tile 0; barrier
  STAGE_A(0); STAGE_B(0);
  STAGE_A(1); STAGE_B(1);
  STAGE_A(2); STAGE_B(2);
  asm volatile("s_waitcnt vmcnt(8)" ::: "memory");
  __builtin_amdgcn_s_barrier();

  for (int kt = 0; kt < nkt; ++kt) {
    const char* slot = lds + ((kt & 3) << 15);
    bf16x8 af[4], bfr[4];

    // ---- P0: B frags + A m0-3, stage A of kt+3
#pragma unroll
    for (int n = 0; n < 4; ++n)
      bfr[n] = *(const bf16x8*)(slot + bBase + (n << 11));
#pragma unroll
    for (int m = 0; m < 4; ++m)
      af[m] = *(const bf16x8*)(slot + aBase + (m << 11));
    if (kt + 3 < nkt) STAGE_A(kt + 3);
    __builtin_amdgcn_s_barrier();
    asm volatile("s_waitcnt lgkmcnt(0)" ::: "memory");
    MFMA_HALF(0)
    __builtin_amdgcn_s_barrier();

    // ---- P1: A m4-7, stage B of kt+3, vmcnt for tile kt+1
#pragma unroll
    for (int m = 0; m < 4; ++m)
      af[m] = *(const bf16x8*)(slot + aBase + ((m + 4) << 11));
    if (kt + 3 < nkt) STAGE_B(kt + 3);
    if (kt < nkt - 3)
      asm volatile("s_waitcnt vmcnt(8)" ::: "memory");
    else if (kt == nkt - 3)
      asm volatile("s_waitcnt vmcnt(4)" ::: "memory");
    else if (kt == nkt - 2)
      asm volatile("s_waitcnt vmcnt(0)" ::: "memory");
    __builtin_amdgcn_s_barrier();
    asm volatile("s_waitcnt lgkmcnt(0)" ::: "memory");
    MFMA_HALF(4)
    __builtin_amdgcn_s_barrier();
  }
#undef STAGE_A
#undef STAGE_B
#undef MFMA_HALF

  // epilogue: C/D layout col = lane&15, row = (lane>>4)*4 + reg  [m89-verified]
  const int cbase = tn * 256 + (wn << 6) + l15;
  float b4[4];
#pragma unroll
  for (int n = 0; n < 4; ++n) b4[n] = bias[cbase + (n << 4)];
  const size_t rbase = (size_t)tm * 256 + (wm << 7) + ((l >> 4) << 2);
#pragma unroll
  for (int m = 0; m < 8; ++m) {
#pragma unroll
    for (int j = 0; j < 4; ++j) {
      const size_t row = rbase + (m << 4) + j;
#pragma unroll
      for (int n = 0; n < 4; ++n) {
        const int col = cbase + (n << 4);
        float v = acc[m][n][j] + b4[n];
        if (OUT_F32)
          ((float*)Cout)[row * N + col] = v;
        else
          ((unsigned short*)Cout)[row * N + col] = f2bf(v);
      }
    }
  }
}

// ---------------------------------------------------------------- attention
// 16 lanes per (b,h); lane x handles dims 4x..4x+3 via ushort4 (8B/lane loads).
__global__ __launch_bounds__(256)
void attn_kernel(const unsigned short* __restrict__ QKV,  // (B*3) x 3072
                 const unsigned short* __restrict__ Cp,   // B x 1024
                 unsigned short* __restrict__ Out) {      // (B*3) x 1024
  const int t = threadIdx.x;
  const int grp = (blockIdx.x << 4) + (t >> 4);
  const int x = t & 15;
  const int b = grp >> 4;   // H = 16
  const int h = grp & 15;

  const size_t col = (size_t)h * 64 + (x << 2);
  const size_t qbase = (size_t)b * 3 * 3072 + col;

  ushort4 cu = *(const ushort4*)&Cp[(size_t)b * 1024 + col];
  float c[4] = {bf2f(cu.x), bf2f(cu.y), bf2f(cu.z), bf2f(cu.w)};

  float q[3][4], kc[3][4], vc[3][4];
#pragma unroll
  for (int i = 0; i < 3; ++i) {
    ushort4 qu = *(const ushort4*)&QKV[qbase + (size_t)i * 3072];
    ushort4 ku = *(const ushort4*)&QKV[qbase + (size_t)i * 3072 + 1024];
    ushort4 vu = *(const ushort4*)&QKV[qbase + (size_t)i * 3072 + 2048];
    q[i][0] = bf2f(qu.x); q[i][1] = bf2f(qu.y); q[i][2] = bf2f(qu.z); q[i][3] = bf2f(qu.w);
    kc[i][0] = bf2f(ku.x) * c[0]; kc[i][1] = bf2f(ku.y) * c[1];
    kc[i][2] = bf2f(ku.z) * c[2]; kc[i][3] = bf2f(ku.w) * c[3];
    vc[i][0] = bf2f(vu.x) * c[0]; vc[i][1] = bf2f(vu.y) * c[1];
    vc[i][2] = bf2f(vu.z) * c[2]; vc[i][3] = bf2f(vu.w) * c[3];
  }

  float s[9];
#pragma unroll
  for (int i = 0; i < 3; ++i)
#pragma unroll
    for (int j = 0; j < 3; ++j)
      s[i * 3 + j] = q[i][0] * kc[j][0] + q[i][1] * kc[j][1] +
                     q[i][2] * kc[j][2] + q[i][3] * kc[j][3];

#pragma unroll
  for (int off = 8; off > 0; off >>= 1)
#pragma unroll
    for (int e = 0; e < 9; ++e)
      s[e] += __shfl_xor(s[e], off, 64);

  const float scale = 0.125f;  // 1/sqrt(64)
#pragma unroll
  for (int i = 0; i < 3; ++i) {
    float s0 = s[i * 3 + 0] * scale;
    float s1 = s[i * 3 + 1] * scale;
    float s2 = s[i * 3 + 2] * scale;
    float m = fmaxf(fmaxf(s0, s1), s2);
    float p0 = expf(s0 - m), p1 = expf(s1 - m), p2 = expf(s2 - m);
    float inv = 1.0f / (p0 + p1 + p2);
    ushort4 o;
    o.x = f2bf((p0 * vc[0][0] + p1 * vc[1][0] + p2 * vc[2][0]) * inv);
    o.y = f2bf((p0 * vc[0][1] + p1 * vc[1][1] + p2 * vc[2][1]) * inv);
    o.z = f2bf((p0 * vc[0][2] + p1 * vc[1][2] + p2 * vc[2][2]) * inv);
    o.w = f2bf((p0 * vc[0][3] + p1 * vc[1][3] + p2 * vc[2][3]) * inv);
    *(ushort4*)&Out[(size_t)(b * 3 + i) * 1024 + col] = o;
  }
}

// ---------------------------------------------------------------- launch
extern "C" void kernel_launch(void* const* d_in, const int* in_sizes, int n_in,
                              void* d_out, int out_size, void* d_ws, size_t ws_size,
                              hipStream_t stream) {
  const float* tokens = (const float*)d_in[0];
  const float* ctx    = (const float*)d_in[1];
  const float* Wq     = (const float*)d_in[2];
  const float* bq     = (const float*)d_in[3];
  const float* Wk     = (const float*)d_in[4];
  const float* bk     = (const float*)d_in[5];
  const float* Wv     = (const float*)d_in[6];
  const float* bv     = (const float*)d_in[7];
  const float* Wc     = (const float*)d_in[8];
  const float* bc     = (const float*)d_in[9];
  const float* Wo     = (const float*)d_in[10];
  const float* bo     = (const float*)d_in[11];

  const int M  = BB * KK;   // 49152 token rows
  const int Mc = BB;        // 16384 ctx rows
  const int D  = DD;        // 1024

  char* p = (char*)d_ws;
  auto carve = [&](size_t bytes) {
    char* r = p;
    p += (bytes + 255) & ~(size_t)255;
    return r;
  };
  unsigned short* Xb   = (unsigned short*)carve((size_t)M * D * 2);  // tokens bf16; reused as attn out
  unsigned short* Cin  = (unsigned short*)carve((size_t)Mc * D * 2);
  unsigned short* Wqkv = (unsigned short*)carve((size_t)3 * D * D * 2);
  unsigned short* Wcb  = (unsigned short*)carve((size_t)D * D * 2);
  unsigned short* Wob  = (unsigned short*)carve((size_t)D * D * 2);
  float*          bqkv = (float*)carve((size_t)3 * D * 4);
  unsigned short* QKV  = (unsigned short*)carve((size_t)M * 3 * D * 2);
  unsigned short* Cpr  = (unsigned short*)carve((size_t)Mc * D * 2);

  hipLaunchKernelGGL(cast_f32_bf16, dim3(4096), dim3(256), 0, stream, tokens, Xb, M * D / 4);
  hipLaunchKernelGGL(cast_f32_bf16, dim3(2048), dim3(256), 0, stream, ctx, Cin, Mc * D / 4);
  hipLaunchKernelGGL(cast_f32_bf16, dim3(512), dim3(256), 0, stream, Wq, Wqkv, D * D / 4);
  hipLaunchKernelGGL(cast_f32_bf16, dim3(512), dim3(256), 0, stream, Wk, Wqkv + D * D, D * D / 4);
  hipLaunchKernelGGL(cast_f32_bf16, dim3(512), dim3(256), 0, stream, Wv, Wqkv + 2 * D * D, D * D / 4);
  hipLaunchKernelGGL(cast_f32_bf16, dim3(512), dim3(256), 0, stream, Wc, Wcb, D * D / 4);
  hipLaunchKernelGGL(cast_f32_bf16, dim3(512), dim3(256), 0, stream, Wo, Wob, D * D / 4);
  hipMemcpyAsync(bqkv, bq, D * 4, hipMemcpyDeviceToDevice, stream);
  hipMemcpyAsync(bqkv + D, bk, D * 4, hipMemcpyDeviceToDevice, stream);
  hipMemcpyAsync(bqkv + 2 * D, bv, D * 4, hipMemcpyDeviceToDevice, stream);

  // QKV projection: (49152 x 1024) @ (1024 x 3072) -> 192*12 = 2304 blocks
  hipLaunchKernelGGL((gemm256<false>), dim3((M / 256) * (3 * D / 256)), dim3(512), 0, stream,
                     (const __hip_bfloat16*)Xb, (const __hip_bfloat16*)Wqkv, bqkv,
                     (void*)QKV, M, 3 * D, D);
  // ctx projection: (16384 x 1024) @ (1024 x 1024) -> 64*4 = 256 blocks
  hipLaunchKernelGGL((gemm256<false>), dim3((Mc / 256) * (D / 256)), dim3(512), 0, stream,
                     (const __hip_bfloat16*)Cin, (const __hip_bfloat16*)Wcb, bc,
                     (void*)Cpr, Mc, D, D);
  // attention (writes into Xb, dead after the QKV GEMM)
  hipLaunchKernelGGL(attn_kernel, dim3(BB * HH / 16), dim3(256), 0, stream, QKV, Cpr, Xb);
  // output projection -> fp32 d_out with bias: 192*4 = 768 blocks
  hipLaunchKernelGGL((gemm256<true>), dim3((M / 256) * (D / 256)), dim3(512), 0, stream,
                     (const __hip_bfloat16*)Xb, (const __hip_bfloat16*)Wob, bo,
                     d_out, M, D, D);
}